// Round 2
// baseline (12661.626 us; speedup 1.0000x reference)
//
#include <hip/hip_runtime.h>
#include <stdint.h>

#define NROWS 131072
#define DDIM  64
#define KCB   1024

#define BLOCK_ROWS 128   // rows per block (4 waves x 32 rows)
#define WROWS      32    // rows per wave
#define CHUNK      64    // k per chunk (= wave width)
#define NCHUNK     (KCB / CHUNK)

__global__ __launch_bounds__(256, 3)
void codebook_l2_kernel(const float* __restrict__ x,
                        const float* __restrict__ cb,
                        float* __restrict__ out_codevec,
                        float* __restrict__ out_codes,
                        float* __restrict__ out_l2) {
    __shared__ float xsq_s[BLOCK_ROWS];
    __shared__ float csq_s[KCB];

    const int tid    = threadIdx.x;
    const int lane   = tid & 63;
    const int wid    = tid >> 6;
    const int rowblk = blockIdx.x * BLOCK_ROWS;

    // ---- prologue: per-row ||x||^2 (128 rows) and ||c||^2 (1024 cols) ----
    if (tid < BLOCK_ROWS) {
        const float4* xr = (const float4*)(x + (size_t)(rowblk + tid) * DDIM);
        float s = 0.f;
#pragma unroll
        for (int q = 0; q < 16; ++q) {
            float4 v = xr[q];
            s = fmaf(v.x, v.x, s); s = fmaf(v.y, v.y, s);
            s = fmaf(v.z, v.z, s); s = fmaf(v.w, v.w, s);
        }
        xsq_s[tid] = s;
    }
#pragma unroll
    for (int j = 0; j < 4; ++j) {
        const int k = tid + j * 256;
        const float4* cr = (const float4*)(cb + (size_t)k * DDIM);
        float s = 0.f;
#pragma unroll
        for (int q = 0; q < 16; ++q) {
            float4 v = cr[q];
            s = fmaf(v.x, v.x, s); s = fmaf(v.y, v.y, s);
            s = fmaf(v.z, v.z, s); s = fmaf(v.w, v.w, s);
        }
        csq_s[k] = s;
    }
    __syncthreads();

    const int wrow = rowblk + wid * WROWS;   // this wave's first row

    float    minv[WROWS];
    uint32_t pack[WROWS / 8];                // 4-bit chunk id per row
#pragma unroll
    for (int r = 0; r < WROWS; ++r) minv[r] = 3.4e38f;
#pragma unroll
    for (int p = 0; p < WROWS / 8; ++p) pack[p] = 0u;

    for (int chunk = 0; chunk < NCHUNK; ++chunk) {
        const int k0 = chunk << 6;

        // lane's codebook row for this chunk -> 64 VGPRs
        float4 cq[16];
        const float4* cp = (const float4*)(cb + (size_t)(k0 + lane) * DDIM);
#pragma unroll
        for (int q = 0; q < 16; ++q) cq[q] = cp[q];

        const float csql = csq_s[k0 + lane];

        uint32_t sh[8];
#pragma unroll
        for (int j = 0; j < 8; ++j) sh[j] = ((uint32_t)chunk) << (4 * j);

#pragma unroll
        for (int g = 0; g < 8; ++g) {
            float acc0 = 0.f, acc1 = 0.f, acc2 = 0.f, acc3 = 0.f;
            const float4* xr0 = (const float4*)(x + (size_t)(wrow + g * 4 + 0) * DDIM);
            const float4* xr1 = (const float4*)(x + (size_t)(wrow + g * 4 + 1) * DDIM);
            const float4* xr2 = (const float4*)(x + (size_t)(wrow + g * 4 + 2) * DDIM);
            const float4* xr3 = (const float4*)(x + (size_t)(wrow + g * 4 + 3) * DDIM);
#pragma unroll
            for (int q = 0; q < 16; ++q) {
                float4 c4 = cq[q];
                float4 a0 = xr0[q], a1 = xr1[q], a2 = xr2[q], a3 = xr3[q];
                acc0 = fmaf(a0.x, c4.x, acc0); acc0 = fmaf(a0.y, c4.y, acc0);
                acc0 = fmaf(a0.z, c4.z, acc0); acc0 = fmaf(a0.w, c4.w, acc0);
                acc1 = fmaf(a1.x, c4.x, acc1); acc1 = fmaf(a1.y, c4.y, acc1);
                acc1 = fmaf(a1.z, c4.z, acc1); acc1 = fmaf(a1.w, c4.w, acc1);
                acc2 = fmaf(a2.x, c4.x, acc2); acc2 = fmaf(a2.y, c4.y, acc2);
                acc2 = fmaf(a2.z, c4.z, acc2); acc2 = fmaf(a2.w, c4.w, acc2);
                acc3 = fmaf(a3.x, c4.x, acc3); acc3 = fmaf(a3.y, c4.y, acc3);
                acc3 = fmaf(a3.z, c4.z, acc3); acc3 = fmaf(a3.w, c4.w, acc3);
            }
#pragma unroll
            for (int i = 0; i < 4; ++i) {
                const int r = g * 4 + i;
                const float a = (i == 0) ? acc0 : (i == 1) ? acc1 : (i == 2) ? acc2 : acc3;
                const float l2 = fmaf(-2.f, a, xsq_s[wid * WROWS + r] + csql);
                out_l2[(size_t)(wrow + r) * KCB + k0 + lane] = l2;
                const bool c = l2 < minv[r];
                const uint32_t np = (pack[r >> 3] & ~(0xFu << (4 * (r & 7)))) | sh[r & 7];
                minv[r]     = c ? l2 : minv[r];
                pack[r >> 3] = c ? np : pack[r >> 3];
            }
        }
    }

    // ---- final: cross-lane argmin per row, codes + code_vec ----
#pragma unroll
    for (int r = 0; r < WROWS; ++r) {
        float v   = minv[r];
        int   idx = (int)(((pack[r >> 3] >> (4 * (r & 7))) & 0xFu) << 6) | lane;
#pragma unroll
        for (int m = 1; m < 64; m <<= 1) {
            float ov = __shfl_xor(v, m);
            int   oi = __shfl_xor(idx, m);
            if (ov < v || (ov == v && oi < idx)) { v = ov; idx = oi; }
        }
        const int row = wrow + r;
        if (lane == 0) out_codes[row] = (float)idx;
        out_codevec[(size_t)row * DDIM + lane] = cb[(size_t)idx * DDIM + lane];
    }
}

extern "C" void kernel_launch(void* const* d_in, const int* in_sizes, int n_in,
                              void* d_out, int out_size, void* d_ws, size_t ws_size,
                              hipStream_t stream) {
    (void)in_sizes; (void)n_in; (void)d_ws; (void)ws_size; (void)out_size;
    const float* x  = (const float*)d_in[0];
    const float* cb = (const float*)d_in[1];

    float* out_codevec = (float*)d_out;                       // N*D
    float* out_codes   = out_codevec + (size_t)NROWS * DDIM;  // N
    float* out_l2      = out_codes + NROWS;                   // N*K

    dim3 grid(NROWS / BLOCK_ROWS);
    dim3 block(256);
    codebook_l2_kernel<<<grid, block, 0, stream>>>(x, cb, out_codevec, out_codes, out_l2);
}

// Round 3
// 771.594 us; speedup vs baseline: 16.4097x; 16.4097x over previous
//
#include <hip/hip_runtime.h>
#include <stdint.h>

#define NROWS 131072
#define DDIM  64
#define KCB   1024
#define CHUNKS 16            // KCB / 64
#define RPW    16            // rows per wave
#define WPB    4             // waves per block
#define BLOCK_THREADS 256

typedef float f32x16 __attribute__((ext_vector_type(16)));

#define FMA4(ACC, CQ, XV, q)                 \
    ACC = fmaf((CQ).x, (XV)[4*(q)+0], ACC);  \
    ACC = fmaf((CQ).y, (XV)[4*(q)+1], ACC);  \
    ACC = fmaf((CQ).z, (XV)[4*(q)+2], ACC);  \
    ACC = fmaf((CQ).w, (XV)[4*(q)+3], ACC);

__global__ __launch_bounds__(BLOCK_THREADS, 3)
void codebook_l2_kernel(const float* __restrict__ x,
                        const float* __restrict__ cb,
                        float* __restrict__ out_codevec,
                        float* __restrict__ out_codes,
                        float* __restrict__ out_l2) {
    const int tid  = threadIdx.x;
    const int lane = tid & 63;
    const int wid  = tid >> 6;
    const int rowbase = (blockIdx.x * WPB + wid) * RPW;

    // ---- prologue: ||x||^2 for this wave's 16 rows, broadcast to all lanes ----
    float xsqv[RPW];
    {
        const int r = lane & 15;
        const float4* xr = (const float4*)(x + (size_t)(rowbase + r) * DDIM);
        float s = 0.f;
#pragma unroll
        for (int q = 0; q < 16; ++q) {
            float4 v = xr[q];
            s = fmaf(v.x, v.x, s); s = fmaf(v.y, v.y, s);
            s = fmaf(v.z, v.z, s); s = fmaf(v.w, v.w, s);
        }
#pragma unroll
        for (int r2 = 0; r2 < RPW; ++r2) xsqv[r2] = __shfl(s, r2);
    }

    float minv[RPW];
#pragma unroll
    for (int r = 0; r < RPW; ++r) minv[r] = 3.4e38f;
    uint32_t pack0 = 0u, pack1 = 0u;   // 4-bit chunk id per row (rows 0-7 / 8-15)

    for (int chunk = 0; chunk < CHUNKS; ++chunk) {
        const int k0 = chunk << 6;

        // lane's codebook row for this chunk -> 64 VGPRs
        float4 cq[16];
        const float4* cp = (const float4*)(cb + (size_t)(k0 + lane) * DDIM);
#pragma unroll
        for (int q = 0; q < 16; ++q) cq[q] = cp[q];

        // ||c||^2 for lane's column (4 independent chains)
        float cs0 = 0.f, cs1 = 0.f, cs2 = 0.f, cs3 = 0.f;
#pragma unroll
        for (int q = 0; q < 4; ++q) {
            cs0 = fmaf(cq[q].x, cq[q].x, cs0);       cs0 = fmaf(cq[q].y, cq[q].y, cs0);
            cs0 = fmaf(cq[q].z, cq[q].z, cs0);       cs0 = fmaf(cq[q].w, cq[q].w, cs0);
            cs1 = fmaf(cq[4+q].x, cq[4+q].x, cs1);   cs1 = fmaf(cq[4+q].y, cq[4+q].y, cs1);
            cs1 = fmaf(cq[4+q].z, cq[4+q].z, cs1);   cs1 = fmaf(cq[4+q].w, cq[4+q].w, cs1);
            cs2 = fmaf(cq[8+q].x, cq[8+q].x, cs2);   cs2 = fmaf(cq[8+q].y, cq[8+q].y, cs2);
            cs2 = fmaf(cq[8+q].z, cq[8+q].z, cs2);   cs2 = fmaf(cq[8+q].w, cq[8+q].w, cs2);
            cs3 = fmaf(cq[12+q].x, cq[12+q].x, cs3); cs3 = fmaf(cq[12+q].y, cq[12+q].y, cs3);
            cs3 = fmaf(cq[12+q].z, cq[12+q].z, cs3); cs3 = fmaf(cq[12+q].w, cq[12+q].w, cs3);
        }
        const float cs = (cs0 + cs1) + (cs2 + cs3);

#pragma unroll
        for (int r = 0; r < RPW; ++r) {
            // wave-uniform x-row pointer -> SGPR pair
            uint64_t a  = (uint64_t)(x + (size_t)(rowbase + r) * DDIM);
            uint32_t lo = __builtin_amdgcn_readfirstlane((uint32_t)a);
            uint32_t hi = __builtin_amdgcn_readfirstlane((uint32_t)(a >> 32));
            const float* xr = (const float*)(((uint64_t)hi << 32) | lo);

            f32x16 x0, x1, x2, x3;
            asm volatile("s_load_dwordx16 %0, %1, 0x0"  : "=s"(x0) : "s"(xr));
            asm volatile("s_load_dwordx16 %0, %1, 0x40" : "=s"(x1) : "s"(xr));
            asm volatile("s_load_dwordx16 %0, %1, 0x80" : "=s"(x2) : "s"(xr));
            asm volatile("s_load_dwordx16 %0, %1, 0xc0" : "=s"(x3) : "s"(xr));
            // dataflow-tied wait: FMAs below depend on these outputs
            asm volatile("s_waitcnt lgkmcnt(0)"
                         : "+s"(x0), "+s"(x1), "+s"(x2), "+s"(x3));
            __builtin_amdgcn_sched_barrier(0);

            float a0 = 0.f, a1 = 0.f, a2 = 0.f, a3 = 0.f;
#pragma unroll
            for (int q = 0; q < 4; ++q) {
                FMA4(a0, cq[q],      x0, q)
                FMA4(a1, cq[4 + q],  x1, q)
                FMA4(a2, cq[8 + q],  x2, q)
                FMA4(a3, cq[12 + q], x3, q)
            }
            const float dot = (a0 + a1) + (a2 + a3);
            const float l2  = fmaf(-2.f, dot, xsqv[r] + cs);

            out_l2[(size_t)(rowbase + r) * KCB + k0 + lane] = l2;

            const bool cpred = l2 < minv[r];
            minv[r] = cpred ? l2 : minv[r];
            if (r < 8) {
                const uint32_t np = (pack0 & ~(0xFu << (4 * r))) | ((uint32_t)chunk << (4 * r));
                pack0 = cpred ? np : pack0;
            } else {
                const uint32_t np = (pack1 & ~(0xFu << (4 * (r - 8)))) | ((uint32_t)chunk << (4 * (r - 8)));
                pack1 = cpred ? np : pack1;
            }
        }
    }

    // ---- epilogue: cross-lane argmin per row, codes + code_vec ----
#pragma unroll
    for (int r = 0; r < RPW; ++r) {
        float v = minv[r];
        const uint32_t cbits = (r < 8) ? ((pack0 >> (4 * r)) & 0xFu)
                                       : ((pack1 >> (4 * (r - 8))) & 0xFu);
        int idx = (int)((cbits << 6) | (uint32_t)lane);
#pragma unroll
        for (int m = 1; m < 64; m <<= 1) {
            float ov = __shfl_xor(v, m);
            int   oi = __shfl_xor(idx, m);
            if (ov < v || (ov == v && oi < idx)) { v = ov; idx = oi; }
        }
        const int row = rowbase + r;
        if (lane == 0) out_codes[row] = (float)idx;
        out_codevec[(size_t)row * DDIM + lane] = cb[(size_t)idx * DDIM + lane];
    }
}

extern "C" void kernel_launch(void* const* d_in, const int* in_sizes, int n_in,
                              void* d_out, int out_size, void* d_ws, size_t ws_size,
                              hipStream_t stream) {
    (void)in_sizes; (void)n_in; (void)d_ws; (void)ws_size; (void)out_size;
    const float* x  = (const float*)d_in[0];
    const float* cb = (const float*)d_in[1];

    float* out_codevec = (float*)d_out;                       // N*D
    float* out_codes   = out_codevec + (size_t)NROWS * DDIM;  // N
    float* out_l2      = out_codes + NROWS;                   // N*K

    dim3 grid(NROWS / (RPW * WPB));
    dim3 block(BLOCK_THREADS);
    codebook_l2_kernel<<<grid, block, 0, stream>>>(x, cb, out_codevec, out_codes, out_l2);
}

// Round 4
// 221.233 us; speedup vs baseline: 57.2321x; 3.4877x over previous
//
#include <hip/hip_runtime.h>
#include <stdint.h>

#define NROWS 131072
#define DDIM  64
#define KCB   1024
#define BM    128          // rows per block (4 waves x 32)
#define NCHUNK 16          // K chunks of 64 cols

typedef short bf16x8 __attribute__((ext_vector_type(8)));
typedef float f32x4  __attribute__((ext_vector_type(4)));

__device__ __forceinline__ unsigned short f2bf(float f) {
    unsigned int u = __float_as_uint(f);
    u += 0x7FFFu + ((u >> 16) & 1u);
    return (unsigned short)(u >> 16);
}
__device__ __forceinline__ float bf2f(unsigned short h) {
    return __uint_as_float(((unsigned int)h) << 16);
}

// ---- pre-kernel: codebook -> bf16 hi/lo planes + ||c||^2 (fp32) into ws ----
__global__ __launch_bounds__(256)
void convert_cb(const float* __restrict__ cb,
                unsigned short* __restrict__ cbh,
                unsigned short* __restrict__ cbl,
                float* __restrict__ csq) {
    const int k = blockIdx.x * 256 + threadIdx.x;    // 1024 threads total
    const float4* src = (const float4*)(cb + (size_t)k * DDIM);
    unsigned short* dh = cbh + (size_t)k * DDIM;
    unsigned short* dl = cbl + (size_t)k * DDIM;
    float s0 = 0.f, s1 = 0.f, s2 = 0.f, s3 = 0.f;
#pragma unroll
    for (int q = 0; q < 16; ++q) {
        float4 v = src[q];
        unsigned short hb;
        hb = f2bf(v.x); dh[q*4+0] = hb; dl[q*4+0] = f2bf(v.x - bf2f(hb));
        hb = f2bf(v.y); dh[q*4+1] = hb; dl[q*4+1] = f2bf(v.y - bf2f(hb));
        hb = f2bf(v.z); dh[q*4+2] = hb; dl[q*4+2] = f2bf(v.z - bf2f(hb));
        hb = f2bf(v.w); dh[q*4+3] = hb; dl[q*4+3] = f2bf(v.w - bf2f(hb));
        s0 = fmaf(v.x, v.x, s0); s1 = fmaf(v.y, v.y, s1);
        s2 = fmaf(v.z, v.z, s2); s3 = fmaf(v.w, v.w, s3);
    }
    csq[k] = (s0 + s1) + (s2 + s3);
}

__device__ __forceinline__ void cvt8(float4 f0, float4 f1, bf16x8* h, bf16x8* l) {
    bf16x8 hh, ll;
    float fv; unsigned short hb;
    fv = f0.x; hb = f2bf(fv); hh[0] = (short)hb; ll[0] = (short)f2bf(fv - bf2f(hb));
    fv = f0.y; hb = f2bf(fv); hh[1] = (short)hb; ll[1] = (short)f2bf(fv - bf2f(hb));
    fv = f0.z; hb = f2bf(fv); hh[2] = (short)hb; ll[2] = (short)f2bf(fv - bf2f(hb));
    fv = f0.w; hb = f2bf(fv); hh[3] = (short)hb; ll[3] = (short)f2bf(fv - bf2f(hb));
    fv = f1.x; hb = f2bf(fv); hh[4] = (short)hb; ll[4] = (short)f2bf(fv - bf2f(hb));
    fv = f1.y; hb = f2bf(fv); hh[5] = (short)hb; ll[5] = (short)f2bf(fv - bf2f(hb));
    fv = f1.z; hb = f2bf(fv); hh[6] = (short)hb; ll[6] = (short)f2bf(fv - bf2f(hb));
    fv = f1.w; hb = f2bf(fv); hh[7] = (short)hb; ll[7] = (short)f2bf(fv - bf2f(hb));
    *h = hh; *l = ll;
}

__global__ __launch_bounds__(256, 3)
void codebook_mfma(const float* __restrict__ x,
                   const float* __restrict__ cb,
                   const unsigned short* __restrict__ cbh,
                   const unsigned short* __restrict__ cbl,
                   const float* __restrict__ csq,
                   float* __restrict__ out_codevec,
                   float* __restrict__ out_codes,
                   float* __restrict__ out_l2) {
    __shared__ float xs[BM][DDIM];     // fp32 x tile, kept for refinement
    __shared__ float xsq_s[BM];
    __shared__ int   cand_s[BM][2];

    const int tid  = threadIdx.x;
    const int lane = tid & 63;
    const int wid  = tid >> 6;
    const int row0 = blockIdx.x * BM;

    // ---- stage x (fp32, coalesced) + per-row ||x||^2 ----
    {
        const int r = tid >> 1, h = tid & 1;
        const float4* src = (const float4*)(x + (size_t)(row0 + r) * DDIM + h * 32);
        float4* dst = (float4*)&xs[r][h * 32];
        float s0 = 0.f, s1 = 0.f;
#pragma unroll
        for (int q = 0; q < 8; ++q) {
            float4 v = src[q];
            dst[q] = v;
            s0 = fmaf(v.x, v.x, s0); s0 = fmaf(v.y, v.y, s0);
            s1 = fmaf(v.z, v.z, s1); s1 = fmaf(v.w, v.w, s1);
        }
        float s = s0 + s1;
        s += __shfl_xor(s, 1);
        if (h == 0) xsq_s[r] = s;
    }
    __syncthreads();

    const int mrow = wid * 32;     // wave's first row within block
    const int cl   = lane & 15;
    const int ch   = lane >> 4;

    // ---- A fragments (x hi/lo), formed once; layout: row=cl, k=ks*32+ch*8+j ----
    bf16x8 ah[2][2], al[2][2];
#pragma unroll
    for (int mt = 0; mt < 2; ++mt)
#pragma unroll
    for (int ks = 0; ks < 2; ++ks) {
        const float* p = &xs[mrow + mt * 16 + cl][ks * 32 + ch * 8];
        cvt8(*(const float4*)p, *(const float4*)(p + 4), &ah[mt][ks], &al[mt][ks]);
    }

    float xq[2][4];
#pragma unroll
    for (int mt = 0; mt < 2; ++mt)
#pragma unroll
    for (int rg = 0; rg < 4; ++rg)
        xq[mt][rg] = xsq_s[mrow + mt * 16 + ch * 4 + rg];

    float m1[2][4], m2[2][4];
    int   i1[2][4], i2[2][4];
#pragma unroll
    for (int mt = 0; mt < 2; ++mt)
#pragma unroll
    for (int rg = 0; rg < 4; ++rg) {
        m1[mt][rg] = 3.4e38f; m2[mt][rg] = 3.4e38f;
        i1[mt][rg] = 0;       i2[mt][rg] = 0;
    }

    for (int chunk = 0; chunk < NCHUNK; ++chunk) {
        const int k0 = chunk << 6;
#pragma unroll
        for (int nt = 0; nt < 4; ++nt) {
            const int ncol = k0 + nt * 16 + cl;     // B col = codebook index
            const size_t bof = (size_t)ncol * DDIM + ch * 8;
            bf16x8 bh0 = *(const bf16x8*)(cbh + bof);
            bf16x8 bh1 = *(const bf16x8*)(cbh + bof + 32);
            bf16x8 bl0 = *(const bf16x8*)(cbl + bof);
            bf16x8 bl1 = *(const bf16x8*)(cbl + bof + 32);
            const float cq = csq[ncol];
#pragma unroll
            for (int mt = 0; mt < 2; ++mt) {
                f32x4 a = {0.f, 0.f, 0.f, 0.f};
                a = __builtin_amdgcn_mfma_f32_16x16x32_bf16(ah[mt][0], bh0, a, 0, 0, 0);
                a = __builtin_amdgcn_mfma_f32_16x16x32_bf16(ah[mt][1], bh1, a, 0, 0, 0);
                a = __builtin_amdgcn_mfma_f32_16x16x32_bf16(ah[mt][0], bl0, a, 0, 0, 0);
                a = __builtin_amdgcn_mfma_f32_16x16x32_bf16(ah[mt][1], bl1, a, 0, 0, 0);
                a = __builtin_amdgcn_mfma_f32_16x16x32_bf16(al[mt][0], bh0, a, 0, 0, 0);
                a = __builtin_amdgcn_mfma_f32_16x16x32_bf16(al[mt][1], bh1, a, 0, 0, 0);
#pragma unroll
                for (int rg = 0; rg < 4; ++rg) {
                    const float l2 = fmaf(-2.f, a[rg], xq[mt][rg] + cq);
                    out_l2[(size_t)(row0 + mrow + mt * 16 + ch * 4 + rg) * KCB + ncol] = l2;
                    const bool c1 = l2 < m1[mt][rg];
                    const bool c2 = l2 < m2[mt][rg];
                    const float nm2 = c1 ? m1[mt][rg] : (c2 ? l2 : m2[mt][rg]);
                    const int   ni2 = c1 ? i1[mt][rg] : (c2 ? ncol : i2[mt][rg]);
                    m2[mt][rg] = nm2; i2[mt][rg] = ni2;
                    m1[mt][rg] = c1 ? l2 : m1[mt][rg];
                    i1[mt][rg] = c1 ? ncol : i1[mt][rg];
                }
            }
        }
    }

    // ---- top-2 butterfly across the 16 lanes sharing each row ----
#pragma unroll
    for (int mt = 0; mt < 2; ++mt)
#pragma unroll
    for (int rg = 0; rg < 4; ++rg) {
        float a1 = m1[mt][rg], a2 = m2[mt][rg];
        int   j1 = i1[mt][rg], j2 = i2[mt][rg];
#pragma unroll
        for (int mm = 1; mm < 16; mm <<= 1) {
            float o1 = __shfl_xor(a1, mm), o2 = __shfl_xor(a2, mm);
            int   q1 = __shfl_xor(j1, mm), q2 = __shfl_xor(j2, mm);
            const bool fw = (o1 < a1) || (o1 == a1 && q1 < j1);
            const float w1 = fw ? o1 : a1; const int wj1 = fw ? q1 : j1;
            const float ca = fw ? a1 : o1; const int cja = fw ? j1 : q1;
            const float cbv = fw ? o2 : a2; const int cjb = fw ? q2 : j2;
            const bool sw = (cbv < ca) || (cbv == ca && cjb < cja);
            a1 = w1; j1 = wj1;
            a2 = sw ? cbv : ca; j2 = sw ? cjb : cja;
        }
        if (cl == 0) {
            const int r = mrow + mt * 16 + ch * 4 + rg;
            cand_s[r][0] = j1; cand_s[r][1] = j2;
        }
    }
    __syncthreads();

    // ---- fp32 refinement of top-2, codes + code_vec ----
    {
        const int r = tid >> 1, h = tid & 1;
        const int cand = cand_s[r][h];
        const float4* xr = (const float4*)&xs[r][0];
        const float4* cr = (const float4*)(cb + (size_t)cand * DDIM);
        float s0 = 0.f, s1 = 0.f, s2 = 0.f, s3 = 0.f;
#pragma unroll
        for (int q = 0; q < 4; ++q) {
            float4 xa, ca;
            xa = xr[q];      ca = cr[q];
            s0 = fmaf(xa.x, ca.x, s0); s0 = fmaf(xa.y, ca.y, s0);
            s0 = fmaf(xa.z, ca.z, s0); s0 = fmaf(xa.w, ca.w, s0);
            xa = xr[q + 4];  ca = cr[q + 4];
            s1 = fmaf(xa.x, ca.x, s1); s1 = fmaf(xa.y, ca.y, s1);
            s1 = fmaf(xa.z, ca.z, s1); s1 = fmaf(xa.w, ca.w, s1);
            xa = xr[q + 8];  ca = cr[q + 8];
            s2 = fmaf(xa.x, ca.x, s2); s2 = fmaf(xa.y, ca.y, s2);
            s2 = fmaf(xa.z, ca.z, s2); s2 = fmaf(xa.w, ca.w, s2);
            xa = xr[q + 12]; ca = cr[q + 12];
            s3 = fmaf(xa.x, ca.x, s3); s3 = fmaf(xa.y, ca.y, s3);
            s3 = fmaf(xa.z, ca.z, s3); s3 = fmaf(xa.w, ca.w, s3);
        }
        const float dot = (s0 + s1) + (s2 + s3);
        const float d = fmaf(-2.f, dot, xsq_s[r] + csq[cand]);
        const float od = __shfl_xor(d, 1);
        const int   oc = __shfl_xor(cand, 1);
        const bool win = (d < od) || (d == od && cand < oc);
        const int w = win ? cand : oc;
        if (h == 0) out_codes[row0 + r] = (float)w;
        const float4* wv = (const float4*)(cb + (size_t)w * DDIM + h * 32);
        float4* ov = (float4*)(out_codevec + (size_t)(row0 + r) * DDIM + h * 32);
#pragma unroll
        for (int q = 0; q < 8; ++q) ov[q] = wv[q];
    }
}

extern "C" void kernel_launch(void* const* d_in, const int* in_sizes, int n_in,
                              void* d_out, int out_size, void* d_ws, size_t ws_size,
                              hipStream_t stream) {
    (void)in_sizes; (void)n_in; (void)out_size; (void)ws_size;
    const float* x  = (const float*)d_in[0];
    const float* cb = (const float*)d_in[1];

    unsigned short* cbh = (unsigned short*)d_ws;                 // 128 KB
    unsigned short* cbl = cbh + (size_t)KCB * DDIM;              // 128 KB
    float*          csq = (float*)(cbl + (size_t)KCB * DDIM);    // 4 KB

    float* out_codevec = (float*)d_out;                          // N*D
    float* out_codes   = out_codevec + (size_t)NROWS * DDIM;     // N
    float* out_l2      = out_codes + NROWS;                      // N*K

    convert_cb<<<KCB / 256, 256, 0, stream>>>(cb, cbh, cbl, csq);
    codebook_mfma<<<NROWS / BM, 256, 0, stream>>>(x, cb, cbh, cbl, csq,
                                                  out_codevec, out_codes, out_l2);
}